// Round 9
// baseline (1857.113 us; speedup 1.0000x reference)
//
#include <hip/hip_runtime.h>
#include <math.h>

#define NPTS 8192
#define NPOINT 1024
#define NSAMPLE 32

// ---------------------------------------------------------------------------
// u64 max DPP step (2x v_mov_dpp + v_cmp_lt_u64 + 2x cndmask).
// bound_ctrl=true: invalid lanes read 0 = identity for max of our keys (>=0).
// Works for row_shr/row_bcast (wave reduce) and quad_perm (4-lane reduce).
// ---------------------------------------------------------------------------
template <int CTRL>
__device__ __forceinline__ unsigned long long dpp_umax64(unsigned long long key) {
  int lo = (int)(unsigned)key;
  int hi = (int)(unsigned)(key >> 32);
  int slo = __builtin_amdgcn_update_dpp(0, lo, CTRL, 0xF, 0xF, true);
  int shi = __builtin_amdgcn_update_dpp(0, hi, CTRL, 0xF, 0xF, true);
  unsigned long long o =
      ((unsigned long long)(unsigned)shi << 32) | (unsigned)slo;
  return (o > key) ? o : key;
}

__device__ __forceinline__ unsigned p1b2(unsigned v) {  // spread 10 bits
  v &= 0x3FFu;
  v = (v | (v << 16)) & 0x030000FFu;
  v = (v | (v << 8)) & 0x0300F00Fu;
  v = (v | (v << 4)) & 0x030C30C3u;
  v = (v | (v << 2)) & 0x09249249u;
  return v;
}

// ---------------------------------------------------------------------------
// FPS v9: Morton-sorted cells (32 pts x 256 cells) in LDS + EXACT pruning +
// compaction. Skipping a cell is bit-exact when L_real >= cellmax (then
// fminf(dist, D)=dist for every point); we test L*(1-1e-4) >= cellmax with
// true rounding error <= ~8*2^-24 — slack only causes extra non-prunes.
// Keys (distbits<<26 | (8191-orig)<<13 | sortedpt): max-key = max dist, ties
// to MIN original index = np.argmax first-occurrence. Distance math exact:
// contract off, ((dx*dx+dy*dy)+dz*dz), fminf.
// Dynamic LDS 151680 B: coord4(x,y,z,dist) 128K + io u16 16K + ck 2K +
// list 2K + red/cnt.
// ---------------------------------------------------------------------------
__global__ __launch_bounds__(256, 1) void fps_kernel(
    const float* __restrict__ xyz, const float4* __restrict__ coord4g,
    const unsigned* __restrict__ io_g32, const float* __restrict__ anch_g,
    float* __restrict__ new_xyz) {
#pragma clang fp contract(off)
  extern __shared__ char smem[];
  float4* coord4 = (float4*)smem;                                   // 131072
  unsigned* ioL32 = (unsigned*)(smem + 131072);                     // 16384
  const unsigned short* ioL16 = (const unsigned short*)(smem + 131072);
  unsigned long long* ck = (unsigned long long*)(smem + 147456);    // 2048
  unsigned* list2 = (unsigned*)(smem + 149504);                     // 2048
  unsigned long long* red = (unsigned long long*)(smem + 151552);   // 64
  unsigned* lcnt = (unsigned*)(smem + 151616);                      // 8

  const int b = blockIdx.x;
  const int t = threadIdx.x;
  // ---- stage sorted planes into LDS; dist init 1e10 (np.full value) ----
  const float4* cg = coord4g + (size_t)b * NPTS;
#pragma unroll
  for (int m = 0; m < 32; ++m) {
    int i = m * 256 + t;
    float4 f = cg[i];
    f.w = 1e10f;
    coord4[i] = f;
  }
  const unsigned* iog = io_g32 + (size_t)b * 4096;  // 8192 u16 = 4096 u32
#pragma unroll
  for (int m = 0; m < 16; ++m) {
    int i = m * 256 + t;
    ioL32[i] = iog[i];
  }
  ck[t] = ((unsigned long long)0x7F800000u) << 26;  // +inf: iter1 all active
  if (t < 2) lcnt[t] = 0;
  // per-thread cell-t anchors -> registers (invariant)
  const float* ag = anch_g + ((size_t)b * 256 + t) * 6;
  const float ax = ag[0], ay = ag[1], az = ag[2];
  const float hx = ag[3], hy = ag[4], hz = ag[5];
  // first centroid = original point 0
  const float* xp0 = xyz + (size_t)b * 3 * NPTS;
  float cx = xp0[0], cy = xp0[NPTS], cz = xp0[2 * NPTS];
  float* outp = new_xyz + (size_t)b * NPOINT * 3;
  if (t == 0) { outp[0] = cx; outp[1] = cy; outp[2] = cz; }
  __syncthreads();

  for (int s = 1; s < NPOINT; ++s) {
    const int p = s & 1;
    // ---- P0: cell bound test (lower bound L on D(p,c) for all p in cell) --
    float tx = fmaxf(fabsf(cx - ax) - hx, 0.f);
    float ty = fmaxf(fabsf(cy - ay) - hy, 0.f);
    float tz = fmaxf(fabsf(cz - az) - hz, 0.f);
    float L = (tx * tx + ty * ty) + tz * tz;
    float ckv = __uint_as_float((unsigned)(ck[t] >> 26));
    bool active = !(L * 0.9999f >= ckv);   // generous slack, prune-safe
    if (active) {
      unsigned pos = atomicAdd(&lcnt[p], 1u);
      list2[p * 256 + pos] = (unsigned)t;
    }
    __syncthreads();                       // #1: list/count visible
    const unsigned A = lcnt[p];
    if (t == 0) lcnt[1 - p] = 0;           // recycle other parity counter
    // ---- P2: compacted pass — 4 threads/cell, 8 pts each, exact update ----
    for (unsigned c0 = 0; c0 < A; c0 += 64) {
      unsigned ci = c0 + ((unsigned)t >> 2);
      if (ci < A) {
        unsigned slab = list2[p * 256 + ci];
        unsigned pb = slab * 32 + ((unsigned)t & 3u) * 8u;
        unsigned long long tk = 0ull;
#pragma unroll
        for (unsigned e = 0; e < 8; ++e) {
          unsigned pt = pb + e;
          float4 f = coord4[pt];
          float dx = f.x - cx;
          float dy = f.y - cy;
          float dz = f.z - cz;
          float d = (dx * dx + dy * dy) + dz * dz;  // exact np order
          float dm = fminf(f.w, d);
          ((float*)&coord4[pt])[3] = dm;            // write back dist only
          unsigned orig = (unsigned)ioL16[pt];
          unsigned long long kk =
              ((unsigned long long)__float_as_uint(dm) << 26) |
              ((unsigned long long)(8191u - orig) << 13) | pt;
          tk = (kk > tk) ? kk : tk;
        }
        tk = dpp_umax64<0xB1>(tk);        // quad_perm [1,0,3,2]
        tk = dpp_umax64<0x4E>(tk);        // quad_perm [2,3,0,1]
        if (((unsigned)t & 3u) == 3u) ck[slab] = tk;  // exact cell argmax key
      }
    }
    __syncthreads();                       // #2: ck updates visible
    // ---- P4: block argmax over 256 cell keys (active fresh + cached) ----
    unsigned long long kk = ck[t];
    kk = dpp_umax64<0x111>(kk);            // row_shr:1
    kk = dpp_umax64<0x112>(kk);            // row_shr:2
    kk = dpp_umax64<0x114>(kk);            // row_shr:4
    kk = dpp_umax64<0x118>(kk);            // row_shr:8
    kk = dpp_umax64<0x142>(kk);            // row_bcast:15
    kk = dpp_umax64<0x143>(kk);            // row_bcast:31
    unsigned wlo = (unsigned)__builtin_amdgcn_readlane((int)(unsigned)kk, 63);
    unsigned whi =
        (unsigned)__builtin_amdgcn_readlane((int)(unsigned)(kk >> 32), 63);
    if ((t & 63) == 0)
      red[p * 4 + (t >> 6)] = ((unsigned long long)whi << 32) | wlo;
    __syncthreads();                       // #3: wave keys visible
    unsigned long long k0 = red[p * 4 + 0];
    unsigned long long k1 = red[p * 4 + 1];
    unsigned long long k2 = red[p * 4 + 2];
    unsigned long long k3 = red[p * 4 + 3];
    unsigned long long ka = (k0 > k1) ? k0 : k1;
    unsigned long long kb = (k2 > k3) ? k2 : k3;
    unsigned long long km = (ka > kb) ? ka : kb;
    unsigned ptw = (unsigned)(km & 8191ull);
    float4 cw = coord4[ptw];               // broadcast LDS read
    cx = cw.x; cy = cw.y; cz = cw.z;
    if (t == 0) { outp[3 * s] = cx; outp[3 * s + 1] = cy; outp[3 * s + 2] = cz; }
  }
}

// ---------------------------------------------------------------------------
// Setup (grid = 4 blocks, one per batch): Morton-key bitonic sort of 8192
// points in LDS, emit sorted coord/origidx planes + per-cell anchor boxes
// (hw inflated 1+2e-6 so bounds are safe upper covers). Sort order affects
// ONLY pruning efficiency, never correctness. Block 0 also builds w3t/scsh.
// ---------------------------------------------------------------------------
__global__ __launch_bounds__(256) void setup_kernel(
    const float* __restrict__ xyz, const float* __restrict__ w3,
    const float* __restrict__ b1, const float* __restrict__ g1, const float* __restrict__ t1,
    const float* __restrict__ m1, const float* __restrict__ v1,
    const float* __restrict__ b2, const float* __restrict__ g2, const float* __restrict__ t2,
    const float* __restrict__ m2, const float* __restrict__ v2,
    const float* __restrict__ b3, const float* __restrict__ g3, const float* __restrict__ t3,
    const float* __restrict__ m3, const float* __restrict__ v3,
    float4* __restrict__ coord4g, unsigned short* __restrict__ io_g,
    float* __restrict__ anch_g, float* __restrict__ w3t, float* __restrict__ scsh) {
  __shared__ unsigned long long skey[NPTS];  // 64 KB
  const int b = blockIdx.x;
  const int t = threadIdx.x;
  const float* xp = xyz + (size_t)b * 3 * NPTS;
#pragma unroll
  for (int m = 0; m < 32; ++m) {
    int i = m * 256 + t;
    float x = xp[i], y = xp[NPTS + i], z = xp[2 * NPTS + i];
    unsigned xi = (unsigned)fminf(fmaxf(x, 0.f) * 1024.f, 1023.f);
    unsigned yi = (unsigned)fminf(fmaxf(y, 0.f) * 1024.f, 1023.f);
    unsigned zi = (unsigned)fminf(fmaxf(z, 0.f) * 1024.f, 1023.f);
    unsigned long long mort =
        ((unsigned long long)p1b2(zi) << 2) |
        ((unsigned long long)p1b2(yi) << 1) | (unsigned long long)p1b2(xi);
    skey[i] = (mort << 13) | (unsigned)i;
  }
  __syncthreads();
  for (int k = 2; k <= NPTS; k <<= 1) {
    for (int j = k >> 1; j > 0; j >>= 1) {
      for (int m = 0; m < 32; ++m) {
        int i = m * 256 + t;
        int ixj = i ^ j;
        if (ixj > i) {
          unsigned long long a = skey[i], c = skey[ixj];
          bool up = ((i & k) == 0);
          if ((a > c) == up) { skey[i] = c; skey[ixj] = a; }
        }
      }
      __syncthreads();
    }
  }
  // sorted planes (gathers are L2-hot: whole 96KB batch read in stage A)
#pragma unroll
  for (int m = 0; m < 32; ++m) {
    int i = m * 256 + t;
    unsigned orig = (unsigned)(skey[i] & 8191ull);
    float x = xp[orig], y = xp[NPTS + orig], z = xp[2 * NPTS + orig];
    coord4g[(size_t)b * NPTS + i] = make_float4(x, y, z, 0.f);
    io_g[(size_t)b * NPTS + i] = (unsigned short)orig;
  }
  __syncthreads();  // block-local global RAW: vmcnt drained at barrier
  // per-cell anchor boxes (cell t = sorted entries [32t, 32t+32))
  {
    float mnx = 1e30f, mny = 1e30f, mnz = 1e30f;
    float mxx = -1e30f, mxy = -1e30f, mxz = -1e30f;
    for (int e = 0; e < 32; ++e) {
      float4 f = coord4g[(size_t)b * NPTS + t * 32 + e];
      mnx = fminf(mnx, f.x); mxx = fmaxf(mxx, f.x);
      mny = fminf(mny, f.y); mxy = fmaxf(mxy, f.y);
      mnz = fminf(mnz, f.z); mxz = fmaxf(mxz, f.z);
    }
    float cax = 0.5f * (mnx + mxx), cay = 0.5f * (mny + mxy), caz = 0.5f * (mnz + mxz);
    float chx = fmaxf(mxx - cax, cax - mnx) * 1.000002f;
    float chy = fmaxf(mxy - cay, cay - mny) * 1.000002f;
    float chz = fmaxf(mxz - caz, caz - mnz) * 1.000002f;
    float* agp = anch_g + ((size_t)b * 256 + t) * 6;
    agp[0] = cax; agp[1] = cay; agp[2] = caz;
    agp[3] = chx; agp[4] = chy; agp[5] = chz;
  }
  if (b != 0) return;
  for (int i = t; i < 8192; i += 256) {
    int o = i >> 6, c = i & 63;
    w3t[c * 128 + o] = w3[i];
  }
  if (t < 64) {
    float s = g1[t] / sqrtf(v1[t] + 1e-5f);
    scsh[t] = s;
    scsh[64 + t] = (b1[t] - m1[t]) * s + t1[t];
    float s2 = g2[t] / sqrtf(v2[t] + 1e-5f);
    scsh[128 + t] = s2;
    scsh[192 + t] = (b2[t] - m2[t]) * s2 + t2[t];
  }
  if (t < 128) {
    float s3 = g3[t] / sqrtf(v3[t] + 1e-5f);
    scsh[256 + t] = s3;
    scsh[384 + t] = (b3[t] - m3[t]) * s3 + t3[t];
  }
}

// ---------------------------------------------------------------------------
// Fused ball-query + gather + MLP(6->64->64->128, BN+ReLU) + max over 32.
// (unchanged from R8: own-wave bq slots, 64KB swizzled act, L3 holds two
// output-channel groups in registers => 1024 ds_read_b128/wave)
// ---------------------------------------------------------------------------
__global__ __launch_bounds__(256, 2) void mlp_kernel(
    const float* __restrict__ xyz, const float* __restrict__ points,
    const float* __restrict__ new_xyz,
    const float* __restrict__ w1, const float* __restrict__ w2,
    const float* __restrict__ w3t, const float* __restrict__ scsh,
    float* __restrict__ out) {
  __shared__ float act[256 * 64];       // exactly 64 KB -> 2 blocks/CU
  float4* act4 = (float4*)act;
  const int tid = threadIdx.x;
  const int wv = tid >> 6, lane = tid & 63;
  const int s0 = blockIdx.x * 8;
  const int b = s0 >> 10;               // 8 | 1024 -> uniform per block
  const int g = tid >> 5;               // center within block
  const int k = tid & 31;               // sample (phase A) / channel lane (L3)
  const int gc = s0 + g;
  const float* xp = xyz + (size_t)b * 3 * NPTS;
  const float* pp = points + (size_t)b * 3 * NPTS;

  // ---- Phase 0: ball query; slots in wave's own 16KB act region ----
  int* slots = (int*)(act + wv * 4096); // 64 ints, overwritten later by act
  {
#pragma clang fp contract(off)
    for (int h = 0; h < 2; ++h) {
      const int hc = s0 + 2 * wv + h;
      const float* cp0 = new_xyz + (size_t)hc * 3;
      const float cx = cp0[0], cy = cp0[1], cz = cp0[2];
      const float asq = (cx * cx + cy * cy) + cz * cz;
      int cnt = 0;
      for (int base = 0; base < NPTS; base += 64) {
        int n = base + lane;
        float x = xp[n], y = xp[NPTS + n], z = xp[2 * NPTS + n];
        float bsq = (x * x + y * y) + z * z;
        float ab = (x * cx + y * cy) + z * cz;
        float sq = (asq + bsq) - 2.0f * ab;
        bool inc = !(sq > 0.01f);       // same f32 threshold as reference
        unsigned long long mk = __ballot(inc);
        int pos = cnt + (int)__popcll(mk & ((1ull << lane) - 1ull));
        if (inc && pos < NSAMPLE) slots[h * 32 + pos] = n;
        cnt += (int)__popcll(mk);
        if (cnt >= NSAMPLE) break;      // wave-uniform
      }
      if (lane < NSAMPLE) {
        int first = slots[h * 32];      // lockstep: all reads before writes
        int v = (lane < cnt) ? slots[h * 32 + lane] : first;
        slots[h * 32 + lane] = v;
      }
    }
  }
  const int n = slots[(g & 1) * 32 + k];  // own-wave slots: no barrier needed

  const float* cp = new_xyz + (size_t)gc * 3;
  float f0 = xp[n] - cp[0];
  float f1 = xp[NPTS + n] - cp[1];
  float f2 = xp[2 * NPTS + n] - cp[2];
  float f3 = pp[n];
  float f4 = pp[NPTS + n];
  float f5 = pp[2 * NPTS + n];
  const float* sc1 = scsh;        const float* sh1 = scsh + 64;
  const float* sc2 = scsh + 128;  const float* sh2 = scsh + 192;
  const float* sc3 = scsh + 256;  const float* sh3 = scsh + 384;
  const int row = tid;

  // ---- L1 ----
#pragma unroll
  for (int oc = 0; oc < 16; ++oc) {
    float va[4];
#pragma unroll
    for (int jj = 0; jj < 4; ++jj) {
      int o = oc * 4 + jj;
      const float* wr = w1 + o * 6;
      float a = f0 * wr[0] + f1 * wr[1] + f2 * wr[2] +
                f3 * wr[3] + f4 * wr[4] + f5 * wr[5];
      va[jj] = fmaxf(a * sc1[o] + sh1[o], 0.f);
    }
    act4[row * 16 + (oc ^ (row & 15))] = make_float4(va[0], va[1], va[2], va[3]);
  }

  // ---- L2 ----
  float acc[64];
#pragma unroll
  for (int o = 0; o < 64; ++o) acc[o] = 0.f;
  for (int cc = 0; cc < 16; ++cc) {
    float4 av = act4[row * 16 + (cc ^ (row & 15))];
#pragma unroll
    for (int o = 0; o < 64; ++o) {
      const float* wr = w2 + o * 64 + cc * 4;
      acc[o] += av.x * wr[0] + av.y * wr[1] + av.z * wr[2] + av.w * wr[3];
    }
  }
#pragma unroll
  for (int oc = 0; oc < 16; ++oc) {
    float va[4];
#pragma unroll
    for (int jj = 0; jj < 4; ++jj) {
      int o = oc * 4 + jj;
      va[jj] = fmaxf(acc[o] * sc2[o] + sh2[o], 0.f);
    }
    act4[row * 16 + (oc ^ (row & 15))] = make_float4(va[0], va[1], va[2], va[3]);
  }
  __syncthreads();

  // ---- L3 + max over k: lane j owns channels {ph*64+j, ph*64+32+j} ----
  const int j = k;
  const int sb = gc & 1023;
  for (int ph = 0; ph < 2; ++ph) {
    int o3a = ph * 64 + j;
    int o3b = o3a + 32;
    float wa[64], wb[64];
#pragma unroll
    for (int c = 0; c < 64; ++c) {
      wa[c] = w3t[c * 128 + o3a];
      wb[c] = w3t[c * 128 + o3b];
    }
    float sca = sc3[o3a], sha = sh3[o3a];
    float scb = sc3[o3b], shb = sh3[o3b];
    float vma = 0.f, vmb = 0.f;
    for (int kk = 0; kk < 32; ++kk) {
      int r2 = g * 32 + kk;
      float a0 = 0.f, a1 = 0.f, a2 = 0.f, a3 = 0.f;
      float b0 = 0.f, b1 = 0.f, b2 = 0.f, b3 = 0.f;
#pragma unroll
      for (int cc = 0; cc < 16; cc += 4) {
        float4 u0 = act4[r2 * 16 + ((cc + 0) ^ (r2 & 15))];
        float4 u1 = act4[r2 * 16 + ((cc + 1) ^ (r2 & 15))];
        float4 u2 = act4[r2 * 16 + ((cc + 2) ^ (r2 & 15))];
        float4 u3 = act4[r2 * 16 + ((cc + 3) ^ (r2 & 15))];
        a0 += u0.x * wa[4*cc+0]  + u0.y * wa[4*cc+1]  + u0.z * wa[4*cc+2]  + u0.w * wa[4*cc+3];
        a1 += u1.x * wa[4*cc+4]  + u1.y * wa[4*cc+5]  + u1.z * wa[4*cc+6]  + u1.w * wa[4*cc+7];
        a2 += u2.x * wa[4*cc+8]  + u2.y * wa[4*cc+9]  + u2.z * wa[4*cc+10] + u2.w * wa[4*cc+11];
        a3 += u3.x * wa[4*cc+12] + u3.y * wa[4*cc+13] + u3.z * wa[4*cc+14] + u3.w * wa[4*cc+15];
        b0 += u0.x * wb[4*cc+0]  + u0.y * wb[4*cc+1]  + u0.z * wb[4*cc+2]  + u0.w * wb[4*cc+3];
        b1 += u1.x * wb[4*cc+4]  + u1.y * wb[4*cc+5]  + u1.z * wb[4*cc+6]  + u1.w * wb[4*cc+7];
        b2 += u2.x * wb[4*cc+8]  + u2.y * wb[4*cc+9]  + u2.z * wb[4*cc+10] + u2.w * wb[4*cc+11];
        b3 += u3.x * wb[4*cc+12] + u3.y * wb[4*cc+13] + u3.z * wb[4*cc+14] + u3.w * wb[4*cc+15];
      }
      float xa = (a0 + a1) + (a2 + a3);
      float xb = (b0 + b1) + (b2 + b3);
      vma = fmaxf(vma, fmaxf(xa * sca + sha, 0.f));
      vmb = fmaxf(vmb, fmaxf(xb * scb + shb, 0.f));
    }
    out[((size_t)b * 128 + o3a) * 1024 + sb] = vma;   // (B,128,1024)
    out[((size_t)b * 128 + o3b) * 1024 + sb] = vmb;
  }
}

// ---------------------------------------------------------------------------
extern "C" void kernel_launch(void* const* d_in, const int* in_sizes, int n_in,
                              void* d_out, int out_size, void* d_ws, size_t ws_size,
                              hipStream_t stream) {
  (void)in_sizes; (void)n_in; (void)out_size; (void)ws_size;
  const float* xyz    = (const float*)d_in[0];
  const float* points = (const float*)d_in[1];
  const float* w1 = (const float*)d_in[2];
  const float* b1 = (const float*)d_in[3];
  const float* g1 = (const float*)d_in[4];
  const float* t1 = (const float*)d_in[5];
  const float* m1 = (const float*)d_in[6];
  const float* v1 = (const float*)d_in[7];
  const float* w2 = (const float*)d_in[8];
  const float* b2 = (const float*)d_in[9];
  const float* g2 = (const float*)d_in[10];
  const float* t2 = (const float*)d_in[11];
  const float* m2 = (const float*)d_in[12];
  const float* v2 = (const float*)d_in[13];
  const float* w3 = (const float*)d_in[14];
  const float* b3 = (const float*)d_in[15];
  const float* g3 = (const float*)d_in[16];
  const float* t3 = (const float*)d_in[17];
  const float* m3 = (const float*)d_in[18];
  const float* v3 = (const float*)d_in[19];

  float* wsf = (float*)d_ws;
  float* new_xyz = wsf;                           // 12288 f
  float* w3t     = wsf + 12288;                   // 8192 f
  float* scsh    = wsf + 20480;                   // 512 f
  float4* coord4g = (float4*)(wsf + 20992);       // 4*8192 float4 = 512 KB
  unsigned short* io_g = (unsigned short*)(wsf + 152064);  // 4*8192 u16 = 64 KB
  float* anch_g  = wsf + 168448;                  // 4*256*6 f = 24 KB
  float* out     = (float*)d_out;                 // (4,128,1024) f32

  hipFuncSetAttribute(reinterpret_cast<const void*>(fps_kernel),
                      hipFuncAttributeMaxDynamicSharedMemorySize, 151680);

  hipLaunchKernelGGL(setup_kernel, dim3(4), dim3(256), 0, stream,
                     xyz, w3, b1, g1, t1, m1, v1, b2, g2, t2, m2, v2,
                     b3, g3, t3, m3, v3, coord4g, io_g, anch_g, w3t, scsh);
  hipLaunchKernelGGL(fps_kernel, dim3(4), dim3(256), 151680, stream,
                     xyz, coord4g, (const unsigned*)io_g, anch_g, new_xyz);
  hipLaunchKernelGGL(mlp_kernel, dim3(512), dim3(256), 0, stream,
                     xyz, points, new_xyz, w1, w2, w3t, scsh, out);
}

// Round 10
// 1457.156 us; speedup vs baseline: 1.2745x; 1.2745x over previous
//
#include <hip/hip_runtime.h>
#include <math.h>

#define NPTS 8192
#define NPOINT 1024
#define NSAMPLE 32

// ---------------------------------------------------------------------------
// u64 max DPP step. bound_ctrl=true: invalid lanes read 0 = identity for max
// of our keys (>= 0). Sequence row_shr1/2/4/8 reduces each 16-lane row into
// its last lane; row_bcast15 merges row pairs (lane31 = max lanes0-31,
// lane63 = max lanes32-63); row_bcast31 completes the full-wave max.
// ---------------------------------------------------------------------------
template <int CTRL>
__device__ __forceinline__ unsigned long long dpp_umax64(unsigned long long key) {
  int lo = (int)(unsigned)key;
  int hi = (int)(unsigned)(key >> 32);
  int slo = __builtin_amdgcn_update_dpp(0, lo, CTRL, 0xF, 0xF, true);
  int shi = __builtin_amdgcn_update_dpp(0, hi, CTRL, 0xF, 0xF, true);
  unsigned long long o =
      ((unsigned long long)(unsigned)shi << 32) | (unsigned)slo;
  return (o > key) ? o : key;
}

// ---------------------------------------------------------------------------
// FPS v10: exact cell pruning with static wave-ownership.
// Cells: 256 slabs of 32 consecutive counting-sorted points. Thread t
// (wave w, lane l) owns cell l*4+((w+l)&3) — adjacent cells spread across
// waves. Per iteration: register-only bound test (anchors + cached cell max)
// -> ballot -> scalar pair loop (2 cells/round, 1 pt/lane, coalesced float2
// LDS) -> segmented DPP cell argmax -> per-wave reduce over own 64 cached
// cell keys -> ONE barrier -> 4-slot tree -> winner coords from LDS.
// Exactness: skipping cell when L*(1-1e-4) >= cellmax is bit-exact
// (fminf(dist,D)=dist for every point; true rounding err <= ~8*2^-24).
// Keys (distbits<<26 | (8191-orig)<<13 | pt): max = max dist, ties -> min
// original index = np.argmax first-occurrence. Distance: contract off,
// ((dx*dx+dy*dy)+dz*dz), fminf — bit-identical to numpy.
// Dynamic LDS 149568 B: xy 64K + zdist 64K + io 16K + ck 2K + red 64.
// ---------------------------------------------------------------------------
__global__ __launch_bounds__(256, 1) void fps_kernel(
    const float* __restrict__ xyz, const float2* __restrict__ sxy_g,
    const float* __restrict__ sz_g, const unsigned* __restrict__ io_g32,
    const float* __restrict__ anch_g, float* __restrict__ new_xyz) {
#pragma clang fp contract(off)
  extern __shared__ char smem[];
  float2* xyL = (float2*)smem;                                    // 65536
  float2* zdL = (float2*)(smem + 65536);                          // 65536
  unsigned* ioL32 = (unsigned*)(smem + 131072);                   // 16384
  const unsigned short* ioL16 = (const unsigned short*)(smem + 131072);
  unsigned long long* ck = (unsigned long long*)(smem + 147456);  // 2048
  unsigned long long* red = (unsigned long long*)(smem + 149504); // 64

  const int b = blockIdx.x;
  const int t = threadIdx.x;
  const int w = t >> 6, l = t & 63;
  const int myCell = l * 4 + ((w + l) & 3);   // bijection threads<->cells

  const float2* sxy = sxy_g + (size_t)b * NPTS;
  const float* sz = sz_g + (size_t)b * NPTS;
#pragma unroll
  for (int m = 0; m < 32; ++m) {
    int i = m * 256 + t;
    xyL[i] = sxy[i];
    zdL[i] = make_float2(sz[i], 1e10f);       // np.full(1e10) exact value
  }
  const unsigned* iog = io_g32 + (size_t)b * 4096;
#pragma unroll
  for (int m = 0; m < 16; ++m) { int i = m * 256 + t; ioL32[i] = iog[i]; }

  const float* ag = anch_g + ((size_t)b * 256 + myCell) * 6;
  const float ax = ag[0], ay = ag[1], az = ag[2];
  const float hx = ag[3], hy = ag[4], hz = ag[5];
  float ckv = __uint_as_float(0x7F800000u);   // +inf: every cell active iter 1

  const float* xp0 = xyz + (size_t)b * 3 * NPTS;
  float cx = xp0[0], cy = xp0[NPTS], cz = xp0[2 * NPTS];
  float* outp = new_xyz + (size_t)b * NPOINT * 3;
  if (t == 0) { outp[0] = cx; outp[1] = cy; outp[2] = cz; }
  __syncthreads();                            // staging visible

  const int half = l >> 5, li = l & 31;
  for (int s = 1; s < NPOINT; ++s) {
    // ---- bound test: registers only ----
    float tx = fmaxf(fabsf(cx - ax) - hx, 0.f);
    float ty = fmaxf(fabsf(cy - ay) - hy, 0.f);
    float tz = fmaxf(fabsf(cz - az) - hz, 0.f);
    float L = (tx * tx + ty * ty) + tz * tz;
    bool active = !(L * 0.9999f >= ckv);      // prune-safe slack
    unsigned long long mask = __ballot(active);   // SGPR: scalar loop driver
    // ---- pair loop: 2 active cells per round, 1 point per lane ----
    while (mask) {
      int c0 = (int)(__ffsll((long long)mask) - 1);
      mask &= mask - 1;
      int c1 = c0;                            // odd count: both halves = c0
      if (mask) { c1 = (int)(__ffsll((long long)mask) - 1); mask &= mask - 1; }
      int cl = half ? c1 : c0;
      int cellC = cl * 4 + ((w + cl) & 3);
      int pt = cellC * 32 + li;
      float2 xy = xyL[pt];                    // coalesced b64
      float2 zd = zdL[pt];
      float dx = xy.x - cx;
      float dy = xy.y - cy;
      float dz = zd.x - cz;
      float d = (dx * dx + dy * dy) + dz * dz;    // exact np order
      float dm = fminf(zd.y, d);
      ((float*)&zdL[pt])[1] = dm;             // stride-2 b32: 2-way = free
      unsigned orig = (unsigned)ioL16[pt];
      unsigned long long kk =
          ((unsigned long long)__float_as_uint(dm) << 26) |
          ((unsigned long long)(8191u - orig) << 13) | (unsigned)pt;
      kk = dpp_umax64<0x111>(kk);             // segmented 32-lane max
      kk = dpp_umax64<0x112>(kk);
      kk = dpp_umax64<0x114>(kk);
      kk = dpp_umax64<0x118>(kk);
      kk = dpp_umax64<0x142>(kk);             // lane31 = cellA, lane63 = cellB
      if (l == 31 || l == 63) ck[cellC] = kk; // idempotent if c1 == c0
    }
    // ---- per-wave reduce over own 64 cells; cache own cell max ----
    unsigned long long kl = ck[myCell];       // wave-local write->read
    ckv = __uint_as_float((unsigned)(kl >> 26));  // next iter's bound test
    unsigned long long kr = kl;
    kr = dpp_umax64<0x111>(kr);
    kr = dpp_umax64<0x112>(kr);
    kr = dpp_umax64<0x114>(kr);
    kr = dpp_umax64<0x118>(kr);
    kr = dpp_umax64<0x142>(kr);
    kr = dpp_umax64<0x143>(kr);               // lane63 = wave max
    if (l == 63) red[(s & 1) * 4 + w] = kr;   // parity dbuf: no 2nd barrier
    __syncthreads();                          // the ONLY barrier per iter
    const unsigned long long* rp = red + (s & 1) * 4;
    unsigned long long k0 = rp[0], k1 = rp[1], k2 = rp[2], k3 = rp[3];
    unsigned long long ka = (k0 > k1) ? k0 : k1;
    unsigned long long kb = (k2 > k3) ? k2 : k3;
    unsigned long long km = (ka > kb) ? ka : kb;
    unsigned ptw = (unsigned)(km & 8191ull);
    float2 xyw = xyL[ptw];                    // broadcast reads
    float zw = zdL[ptw].x;
    cx = xyw.x; cy = xyw.y; cz = zw;
    if (t == 0) { outp[3 * s] = cx; outp[3 * s + 1] = cy; outp[3 * s + 2] = cz; }
  }
}

// ---------------------------------------------------------------------------
// Setup (grid = 4, one block per batch): counting sort by 8x8x4 box cell
// (LDS histogram + Hillis-Steele scan + atomic scatter) -> sorted planes
// sxy/sz/io + per-slab anchor boxes (inflated 1+2e-6). Scatter order is
// nondeterministic but selection is layout-independent (keys decide by dist
// then orig; anchors from actual slab contents). Block 0 also builds
// w3t + BN-folded scale/shift.
// ---------------------------------------------------------------------------
__global__ __launch_bounds__(256, 1) void setup_kernel(
    const float* __restrict__ xyz, const float* __restrict__ w3,
    const float* __restrict__ b1, const float* __restrict__ g1, const float* __restrict__ t1,
    const float* __restrict__ m1, const float* __restrict__ v1,
    const float* __restrict__ b2, const float* __restrict__ g2, const float* __restrict__ t2,
    const float* __restrict__ m2, const float* __restrict__ v2,
    const float* __restrict__ b3, const float* __restrict__ g3, const float* __restrict__ t3,
    const float* __restrict__ m3, const float* __restrict__ v3,
    float2* __restrict__ sxy_g, float* __restrict__ sz_g,
    unsigned short* __restrict__ io_g, float* __restrict__ anch_g,
    float* __restrict__ w3t, float* __restrict__ scsh) {
#pragma clang fp contract(off)
  __shared__ unsigned cnt[256];
  __shared__ unsigned scan[256];
  const int b = blockIdx.x;
  const int t = threadIdx.x;
  const float* xp = xyz + (size_t)b * 3 * NPTS;
  cnt[t] = 0;
  __syncthreads();
  float xr[32], yr[32], zr[32];
  int cr[32];
#pragma unroll
  for (int m = 0; m < 32; ++m) {
    int i = m * 256 + t;
    float x = xp[i], y = xp[NPTS + i], z = xp[2 * NPTS + i];
    int xi = max(0, min((int)(x * 8.f), 7));
    int yi = max(0, min((int)(y * 8.f), 7));
    int zi = max(0, min((int)(z * 4.f), 3));
    int c = (zi << 6) | (yi << 3) | xi;
    xr[m] = x; yr[m] = y; zr[m] = z; cr[m] = c;
    atomicAdd(&cnt[c], 1u);
  }
  __syncthreads();
  unsigned v = cnt[t];
  scan[t] = v;
  __syncthreads();
  for (int off = 1; off < 256; off <<= 1) {   // Hillis-Steele inclusive scan
    unsigned u = (t >= off) ? scan[t - off] : 0u;
    __syncthreads();
    scan[t] += u;
    __syncthreads();
  }
  cnt[t] = scan[t] - v;                       // exclusive base, reused as slot
  __syncthreads();
#pragma unroll
  for (int m = 0; m < 32; ++m) {
    unsigned p = atomicAdd(&cnt[cr[m]], 1u);
    sxy_g[(size_t)b * NPTS + p] = make_float2(xr[m], yr[m]);
    sz_g[(size_t)b * NPTS + p] = zr[m];
    io_g[(size_t)b * NPTS + p] = (unsigned short)(m * 256 + t);
  }
  __syncthreads();                            // drain scatter before re-read
  // per-slab anchors (slab t = sorted [32t, 32t+32))
  {
    float mnx = 1e30f, mny = 1e30f, mnz = 1e30f;
    float mxx = -1e30f, mxy = -1e30f, mxz = -1e30f;
    for (int e = 0; e < 32; ++e) {
      float2 xy = sxy_g[(size_t)b * NPTS + t * 32 + e];
      float z = sz_g[(size_t)b * NPTS + t * 32 + e];
      mnx = fminf(mnx, xy.x); mxx = fmaxf(mxx, xy.x);
      mny = fminf(mny, xy.y); mxy = fmaxf(mxy, xy.y);
      mnz = fminf(mnz, z);    mxz = fmaxf(mxz, z);
    }
    float cax = 0.5f * (mnx + mxx), cay = 0.5f * (mny + mxy), caz = 0.5f * (mnz + mxz);
    float* agp = anch_g + ((size_t)b * 256 + t) * 6;
    agp[0] = cax; agp[1] = cay; agp[2] = caz;
    agp[3] = fmaxf(mxx - cax, cax - mnx) * 1.000002f;
    agp[4] = fmaxf(mxy - cay, cay - mny) * 1.000002f;
    agp[5] = fmaxf(mxz - caz, caz - mnz) * 1.000002f;
  }
  if (b != 0) return;
  for (int i = t; i < 8192; i += 256) {
    int o = i >> 6, c = i & 63;
    w3t[c * 128 + o] = w3[i];
  }
  if (t < 64) {
    float s = g1[t] / sqrtf(v1[t] + 1e-5f);
    scsh[t] = s;
    scsh[64 + t] = (b1[t] - m1[t]) * s + t1[t];
    float s2 = g2[t] / sqrtf(v2[t] + 1e-5f);
    scsh[128 + t] = s2;
    scsh[192 + t] = (b2[t] - m2[t]) * s2 + t2[t];
  }
  if (t < 128) {
    float s3 = g3[t] / sqrtf(v3[t] + 1e-5f);
    scsh[256 + t] = s3;
    scsh[384 + t] = (b3[t] - m3[t]) * s3 + t3[t];
  }
}

// ---------------------------------------------------------------------------
// Fused ball-query + gather + MLP(6->64->64->128, BN+ReLU) + max over 32.
// (unchanged from R8: own-wave bq slots, 64KB swizzled act, L3 holds two
// output-channel groups in registers => 1024 ds_read_b128/wave)
// ---------------------------------------------------------------------------
__global__ __launch_bounds__(256, 2) void mlp_kernel(
    const float* __restrict__ xyz, const float* __restrict__ points,
    const float* __restrict__ new_xyz,
    const float* __restrict__ w1, const float* __restrict__ w2,
    const float* __restrict__ w3t, const float* __restrict__ scsh,
    float* __restrict__ out) {
  __shared__ float act[256 * 64];       // exactly 64 KB -> 2 blocks/CU
  float4* act4 = (float4*)act;
  const int tid = threadIdx.x;
  const int wv = tid >> 6, lane = tid & 63;
  const int s0 = blockIdx.x * 8;
  const int b = s0 >> 10;               // 8 | 1024 -> uniform per block
  const int g = tid >> 5;               // center within block
  const int k = tid & 31;               // sample (phase A) / channel lane (L3)
  const int gc = s0 + g;
  const float* xp = xyz + (size_t)b * 3 * NPTS;
  const float* pp = points + (size_t)b * 3 * NPTS;

  // ---- Phase 0: ball query; slots in wave's own 16KB act region ----
  int* slots = (int*)(act + wv * 4096); // 64 ints, overwritten later by act
  {
#pragma clang fp contract(off)
    for (int h = 0; h < 2; ++h) {
      const int hc = s0 + 2 * wv + h;
      const float* cp0 = new_xyz + (size_t)hc * 3;
      const float cx = cp0[0], cy = cp0[1], cz = cp0[2];
      const float asq = (cx * cx + cy * cy) + cz * cz;
      int cnt = 0;
      for (int base = 0; base < NPTS; base += 64) {
        int n = base + lane;
        float x = xp[n], y = xp[NPTS + n], z = xp[2 * NPTS + n];
        float bsq = (x * x + y * y) + z * z;
        float ab = (x * cx + y * cy) + z * cz;
        float sq = (asq + bsq) - 2.0f * ab;
        bool inc = !(sq > 0.01f);       // same f32 threshold as reference
        unsigned long long mk = __ballot(inc);
        int pos = cnt + (int)__popcll(mk & ((1ull << lane) - 1ull));
        if (inc && pos < NSAMPLE) slots[h * 32 + pos] = n;
        cnt += (int)__popcll(mk);
        if (cnt >= NSAMPLE) break;      // wave-uniform
      }
      if (lane < NSAMPLE) {
        int first = slots[h * 32];      // lockstep: all reads before writes
        int v = (lane < cnt) ? slots[h * 32 + lane] : first;
        slots[h * 32 + lane] = v;
      }
    }
  }
  const int n = slots[(g & 1) * 32 + k];  // own-wave slots: no barrier needed

  const float* cp = new_xyz + (size_t)gc * 3;
  float f0 = xp[n] - cp[0];
  float f1 = xp[NPTS + n] - cp[1];
  float f2 = xp[2 * NPTS + n] - cp[2];
  float f3 = pp[n];
  float f4 = pp[NPTS + n];
  float f5 = pp[2 * NPTS + n];
  const float* sc1 = scsh;        const float* sh1 = scsh + 64;
  const float* sc2 = scsh + 128;  const float* sh2 = scsh + 192;
  const float* sc3 = scsh + 256;  const float* sh3 = scsh + 384;
  const int row = tid;

  // ---- L1 ----
#pragma unroll
  for (int oc = 0; oc < 16; ++oc) {
    float va[4];
#pragma unroll
    for (int jj = 0; jj < 4; ++jj) {
      int o = oc * 4 + jj;
      const float* wr = w1 + o * 6;
      float a = f0 * wr[0] + f1 * wr[1] + f2 * wr[2] +
                f3 * wr[3] + f4 * wr[4] + f5 * wr[5];
      va[jj] = fmaxf(a * sc1[o] + sh1[o], 0.f);
    }
    act4[row * 16 + (oc ^ (row & 15))] = make_float4(va[0], va[1], va[2], va[3]);
  }

  // ---- L2 ----
  float acc[64];
#pragma unroll
  for (int o = 0; o < 64; ++o) acc[o] = 0.f;
  for (int cc = 0; cc < 16; ++cc) {
    float4 av = act4[row * 16 + (cc ^ (row & 15))];
#pragma unroll
    for (int o = 0; o < 64; ++o) {
      const float* wr = w2 + o * 64 + cc * 4;
      acc[o] += av.x * wr[0] + av.y * wr[1] + av.z * wr[2] + av.w * wr[3];
    }
  }
#pragma unroll
  for (int oc = 0; oc < 16; ++oc) {
    float va[4];
#pragma unroll
    for (int jj = 0; jj < 4; ++jj) {
      int o = oc * 4 + jj;
      va[jj] = fmaxf(acc[o] * sc2[o] + sh2[o], 0.f);
    }
    act4[row * 16 + (oc ^ (row & 15))] = make_float4(va[0], va[1], va[2], va[3]);
  }
  __syncthreads();

  // ---- L3 + max over k: lane j owns channels {ph*64+j, ph*64+32+j} ----
  const int j = k;
  const int sb = gc & 1023;
  for (int ph = 0; ph < 2; ++ph) {
    int o3a = ph * 64 + j;
    int o3b = o3a + 32;
    float wa[64], wb[64];
#pragma unroll
    for (int c = 0; c < 64; ++c) {
      wa[c] = w3t[c * 128 + o3a];
      wb[c] = w3t[c * 128 + o3b];
    }
    float sca = sc3[o3a], sha = sh3[o3a];
    float scb = sc3[o3b], shb = sh3[o3b];
    float vma = 0.f, vmb = 0.f;
    for (int kk = 0; kk < 32; ++kk) {
      int r2 = g * 32 + kk;
      float a0 = 0.f, a1 = 0.f, a2 = 0.f, a3 = 0.f;
      float b0 = 0.f, b1 = 0.f, b2 = 0.f, b3 = 0.f;
#pragma unroll
      for (int cc = 0; cc < 16; cc += 4) {
        float4 u0 = act4[r2 * 16 + ((cc + 0) ^ (r2 & 15))];
        float4 u1 = act4[r2 * 16 + ((cc + 1) ^ (r2 & 15))];
        float4 u2 = act4[r2 * 16 + ((cc + 2) ^ (r2 & 15))];
        float4 u3 = act4[r2 * 16 + ((cc + 3) ^ (r2 & 15))];
        a0 += u0.x * wa[4*cc+0]  + u0.y * wa[4*cc+1]  + u0.z * wa[4*cc+2]  + u0.w * wa[4*cc+3];
        a1 += u1.x * wa[4*cc+4]  + u1.y * wa[4*cc+5]  + u1.z * wa[4*cc+6]  + u1.w * wa[4*cc+7];
        a2 += u2.x * wa[4*cc+8]  + u2.y * wa[4*cc+9]  + u2.z * wa[4*cc+10] + u2.w * wa[4*cc+11];
        a3 += u3.x * wa[4*cc+12] + u3.y * wa[4*cc+13] + u3.z * wa[4*cc+14] + u3.w * wa[4*cc+15];
        b0 += u0.x * wb[4*cc+0]  + u0.y * wb[4*cc+1]  + u0.z * wb[4*cc+2]  + u0.w * wb[4*cc+3];
        b1 += u1.x * wb[4*cc+4]  + u1.y * wb[4*cc+5]  + u1.z * wb[4*cc+6]  + u1.w * wb[4*cc+7];
        b2 += u2.x * wb[4*cc+8]  + u2.y * wb[4*cc+9]  + u2.z * wb[4*cc+10] + u2.w * wb[4*cc+11];
        b3 += u3.x * wb[4*cc+12] + u3.y * wb[4*cc+13] + u3.z * wb[4*cc+14] + u3.w * wb[4*cc+15];
      }
      float xa = (a0 + a1) + (a2 + a3);
      float xb = (b0 + b1) + (b2 + b3);
      vma = fmaxf(vma, fmaxf(xa * sca + sha, 0.f));
      vmb = fmaxf(vmb, fmaxf(xb * scb + shb, 0.f));
    }
    out[((size_t)b * 128 + o3a) * 1024 + sb] = vma;   // (B,128,1024)
    out[((size_t)b * 128 + o3b) * 1024 + sb] = vmb;
  }
}

// ---------------------------------------------------------------------------
extern "C" void kernel_launch(void* const* d_in, const int* in_sizes, int n_in,
                              void* d_out, int out_size, void* d_ws, size_t ws_size,
                              hipStream_t stream) {
  (void)in_sizes; (void)n_in; (void)out_size; (void)ws_size;
  const float* xyz    = (const float*)d_in[0];
  const float* points = (const float*)d_in[1];
  const float* w1 = (const float*)d_in[2];
  const float* b1 = (const float*)d_in[3];
  const float* g1 = (const float*)d_in[4];
  const float* t1 = (const float*)d_in[5];
  const float* m1 = (const float*)d_in[6];
  const float* v1 = (const float*)d_in[7];
  const float* w2 = (const float*)d_in[8];
  const float* b2 = (const float*)d_in[9];
  const float* g2 = (const float*)d_in[10];
  const float* t2 = (const float*)d_in[11];
  const float* m2 = (const float*)d_in[12];
  const float* v2 = (const float*)d_in[13];
  const float* w3 = (const float*)d_in[14];
  const float* b3 = (const float*)d_in[15];
  const float* g3 = (const float*)d_in[16];
  const float* t3 = (const float*)d_in[17];
  const float* m3 = (const float*)d_in[18];
  const float* v3 = (const float*)d_in[19];

  float* wsf = (float*)d_ws;
  float* new_xyz = wsf;                             // 12288 f
  float* w3t     = wsf + 12288;                     // 8192 f
  float* scsh    = wsf + 20480;                     // 512 f
  float2* sxy_g  = (float2*)(wsf + 20992);          // 4*8192 float2 = 65536 f
  float* sz_g    = wsf + 86528;                     // 32768 f
  unsigned short* io_g = (unsigned short*)(wsf + 119296);  // 32768 u16 = 16384 f
  float* anch_g  = wsf + 135680;                    // 6144 f
  float* out     = (float*)d_out;                   // (4,128,1024) f32

  hipFuncSetAttribute(reinterpret_cast<const void*>(fps_kernel),
                      hipFuncAttributeMaxDynamicSharedMemorySize, 149568);

  hipLaunchKernelGGL(setup_kernel, dim3(4), dim3(256), 0, stream,
                     xyz, w3, b1, g1, t1, m1, v1, b2, g2, t2, m2, v2,
                     b3, g3, t3, m3, v3, sxy_g, sz_g, io_g, anch_g, w3t, scsh);
  hipLaunchKernelGGL(fps_kernel, dim3(4), dim3(256), 149568, stream,
                     xyz, sxy_g, sz_g, (const unsigned*)io_g, anch_g, new_xyz);
  hipLaunchKernelGGL(mlp_kernel, dim3(512), dim3(256), 0, stream,
                     xyz, points, new_xyz, w1, w2, w3t, scsh, out);
}

// Round 11
// 1426.787 us; speedup vs baseline: 1.3016x; 1.0213x over previous
//
#include <hip/hip_runtime.h>
#include <math.h>

#define NPTS 8192
#define NPOINT 1024
#define NSAMPLE 32

// ---------------------------------------------------------------------------
// u64 max DPP step. bound_ctrl=true: invalid lanes read 0 = identity for max
// of our keys (>= 0). row_shr1/2/4/8 + row_bcast15/31 = full-wave max in
// lane 63; quad_perm 0xB1/0x4E = 4-lane segmented max (R9-proven).
// ---------------------------------------------------------------------------
template <int CTRL>
__device__ __forceinline__ unsigned long long dpp_umax64(unsigned long long key) {
  int lo = (int)(unsigned)key;
  int hi = (int)(unsigned)(key >> 32);
  int slo = __builtin_amdgcn_update_dpp(0, lo, CTRL, 0xF, 0xF, true);
  int shi = __builtin_amdgcn_update_dpp(0, hi, CTRL, 0xF, 0xF, true);
  unsigned long long o =
      ((unsigned long long)(unsigned)shi << 32) | (unsigned)slo;
  return (o > key) ? o : key;
}

// ---------------------------------------------------------------------------
// FPS v11: exact cell pruning, 16 cells per round.
// R10 post-mortem: pair loop = ~11 serial rounds/wave (2 cells/round) with
// full LDS latency exposed each round. v11: rank-compacted active list (no
// atomics, wave-local), then rounds of 16 cells — quad q owns cell
// alist[r*16+q], lane handles 8 consecutive points (8x b64 xy + 8x b64 zd +
// 1x b128 ko16), in-register key tree, 2-step quad_perm DPP, lane ql==3
// writes ck[cell]. Duplicate processing from idx-clamp is idempotent.
// Exactness machinery unchanged from R9/R10 (passed, absmax 0.0390625):
// prune cell iff L*(1-1e-4) >= cellmax (bit-exact: fminf(dist,D)=dist for
// all its points); keys (distbits<<26 | (8191-orig)<<13 | pt) give max dist,
// ties -> min orig = np.argmax first-occurrence; distance contract-off
// ((dx*dx+dy*dy)+dz*dz), fminf — bit-identical to numpy.
// Dynamic LDS 154688 B: xy 67584 (33 f2/cell pad) + zd 67584 + ko 16384 +
// ck 2048 + red 64 + alist 1024.
// ---------------------------------------------------------------------------
__global__ __launch_bounds__(256, 1) void fps_kernel(
    const float* __restrict__ xyz, const float2* __restrict__ sxy_g,
    const float* __restrict__ sz_g, const unsigned* __restrict__ ko_g32,
    const float* __restrict__ anch_g, float* __restrict__ new_xyz) {
#pragma clang fp contract(off)
  extern __shared__ char smem[];
  float2* xyL = (float2*)smem;                                     // 67584
  float2* zdL = (float2*)(smem + 67584);                           // 67584
  unsigned* koL32 = (unsigned*)(smem + 135168);                    // 16384
  const unsigned short* koL16 = (const unsigned short*)(smem + 135168);
  unsigned long long* ck = (unsigned long long*)(smem + 151552);   // 2048
  unsigned long long* red = (unsigned long long*)(smem + 153600);  // 64
  unsigned* alist = (unsigned*)(smem + 153664);                    // 1024

  const int b = blockIdx.x;
  const int t = threadIdx.x;
  const int w = t >> 6, l = t & 63;
  const int myCell = l * 4 + ((w + l) & 3);   // bijection, wave-interleaved

  const float2* sxy = sxy_g + (size_t)b * NPTS;
  const float* sz = sz_g + (size_t)b * NPTS;
#pragma unroll
  for (int m = 0; m < 32; ++m) {
    int i = m * 256 + t;
    int phys = (i >> 5) * 33 + (i & 31);      // padded plane index
    xyL[phys] = sxy[i];
    zdL[phys] = make_float2(sz[i], 1e10f);    // np.full(1e10) exact value
  }
  const unsigned* kog = ko_g32 + (size_t)b * 4096;
#pragma unroll
  for (int m = 0; m < 16; ++m) { int i = m * 256 + t; koL32[i] = kog[i]; }

  const float* ag = anch_g + ((size_t)b * 256 + myCell) * 6;
  const float ax = ag[0], ay = ag[1], az = ag[2];
  const float hx = ag[3], hy = ag[4], hz = ag[5];
  float ckv = __uint_as_float(0x7F800000u);   // +inf: all active on iter 1

  const float* xp0 = xyz + (size_t)b * 3 * NPTS;
  float cx = xp0[0], cy = xp0[NPTS], cz = xp0[2 * NPTS];
  float* outp = new_xyz + (size_t)b * NPOINT * 3;
  if (t == 0) { outp[0] = cx; outp[1] = cy; outp[2] = cz; }
  __syncthreads();                            // staging visible

  unsigned* alw = alist + w * 64;             // wave-private compact list
  const int q = l >> 2, ql = l & 3;
  for (int s = 1; s < NPOINT; ++s) {
    // ---- bound test: registers only ----
    float tx = fmaxf(fabsf(cx - ax) - hx, 0.f);
    float ty = fmaxf(fabsf(cy - ay) - hy, 0.f);
    float tz = fmaxf(fabsf(cz - az) - hz, 0.f);
    float L = (tx * tx + ty * ty) + tz * tz;
    bool active = !(L * 0.9999f >= ckv);      // prune-safe slack
    unsigned long long mask = __ballot(active);
    int A = (int)__popcll(mask);
    if (active) {                             // rank compaction, no atomics
      int rank = (int)__popcll(mask & ((1ull << l) - 1ull));
      alw[rank] = (unsigned)myCell;
    }
    const int rounds = (A + 15) >> 4;         // 16 cells per round
    for (int r = 0; r < rounds; ++r) {
      int idx = r * 16 + q;
      if (idx >= A) idx = A - 1;              // clamp: duplicate = idempotent
      int cellC = (int)alw[idx];              // 4 lanes same addr: broadcast
      int pb = ql * 8;
      int phys = cellC * 33 + pb;
      int lpt = cellC * 32 + pb;              // logical point base
      uint4 k4 = *((const uint4*)(koL16 + lpt));  // 8 u16, 16B aligned b128
      float2 xyv[8], zdv[8];
#pragma unroll
      for (int e = 0; e < 8; ++e) { xyv[e] = xyL[phys + e]; zdv[e] = zdL[phys + e]; }
      unsigned kos[8] = {k4.x & 0xFFFFu, k4.x >> 16, k4.y & 0xFFFFu, k4.y >> 16,
                         k4.z & 0xFFFFu, k4.z >> 16, k4.w & 0xFFFFu, k4.w >> 16};
      unsigned long long keys[8];
#pragma unroll
      for (int e = 0; e < 8; ++e) {
        float dx = xyv[e].x - cx;
        float dy = xyv[e].y - cy;
        float dz = zdv[e].x - cz;
        float d = (dx * dx + dy * dy) + dz * dz;   // exact np order
        float dm = fminf(zdv[e].y, d);
        ((float*)&zdL[phys + e])[1] = dm;          // stride-2 b32: 2-way free
        keys[e] = ((unsigned long long)__float_as_uint(dm) << 26) |
                  ((unsigned long long)kos[e] << 13) | (unsigned)(lpt + e);
      }
#pragma unroll
      for (int st = 1; st < 8; st <<= 1)
#pragma unroll
        for (int e = 0; e < 8; e += 2 * st)
          keys[e] = (keys[e + st] > keys[e]) ? keys[e + st] : keys[e];
      unsigned long long tk = keys[0];
      tk = dpp_umax64<0xB1>(tk);              // quad_perm [1,0,3,2]
      tk = dpp_umax64<0x4E>(tk);              // quad_perm [2,3,0,1]
      if (ql == 3) ck[cellC] = tk;            // exact cell argmax key
    }
    // ---- per-wave reduce over own 64 cells; refresh cached cell max ----
    unsigned long long kl = ck[myCell];       // wave-local write->read
    ckv = __uint_as_float((unsigned)(kl >> 26));
    unsigned long long kr = kl;
    kr = dpp_umax64<0x111>(kr);
    kr = dpp_umax64<0x112>(kr);
    kr = dpp_umax64<0x114>(kr);
    kr = dpp_umax64<0x118>(kr);
    kr = dpp_umax64<0x142>(kr);
    kr = dpp_umax64<0x143>(kr);               // lane63 = wave max
    if (l == 63) red[(s & 1) * 4 + w] = kr;   // parity dbuf: no 2nd barrier
    __syncthreads();                          // the ONLY barrier per iter
    const unsigned long long* rp = red + (s & 1) * 4;
    unsigned long long k0 = rp[0], k1 = rp[1], k2 = rp[2], k3 = rp[3];
    unsigned long long ka = (k0 > k1) ? k0 : k1;
    unsigned long long kb = (k2 > k3) ? k2 : k3;
    unsigned long long km = (ka > kb) ? ka : kb;
    unsigned ptw = (unsigned)(km & 8191ull);  // logical winner index
    int pphys = (int)(ptw >> 5) * 33 + (int)(ptw & 31u);
    float2 xyw = xyL[pphys];                  // broadcast reads
    float zw = zdL[pphys].x;
    cx = xyw.x; cy = xyw.y; cz = zw;
    if (t == 0) { outp[3 * s] = cx; outp[3 * s + 1] = cy; outp[3 * s + 2] = cz; }
  }
}

// ---------------------------------------------------------------------------
// Setup (grid = 4, one block per batch): counting sort by 8x8x4 box cell
// (LDS histogram + scan + atomic scatter) -> sorted planes sxy/sz + ko16
// (= 8191 - original index, pre-negated for the key) + per-slab anchor boxes
// (inflated 1+2e-6). Scatter order nondeterminism cannot affect selection
// (keys decide by dist then orig; anchors from actual slab contents).
// Block 0 also builds w3t + BN-folded scale/shift.
// ---------------------------------------------------------------------------
__global__ __launch_bounds__(256, 1) void setup_kernel(
    const float* __restrict__ xyz, const float* __restrict__ w3,
    const float* __restrict__ b1, const float* __restrict__ g1, const float* __restrict__ t1,
    const float* __restrict__ m1, const float* __restrict__ v1,
    const float* __restrict__ b2, const float* __restrict__ g2, const float* __restrict__ t2,
    const float* __restrict__ m2, const float* __restrict__ v2,
    const float* __restrict__ b3, const float* __restrict__ g3, const float* __restrict__ t3,
    const float* __restrict__ m3, const float* __restrict__ v3,
    float2* __restrict__ sxy_g, float* __restrict__ sz_g,
    unsigned short* __restrict__ ko_g, float* __restrict__ anch_g,
    float* __restrict__ w3t, float* __restrict__ scsh) {
#pragma clang fp contract(off)
  __shared__ unsigned cnt[256];
  __shared__ unsigned scan[256];
  const int b = blockIdx.x;
  const int t = threadIdx.x;
  const float* xp = xyz + (size_t)b * 3 * NPTS;
  cnt[t] = 0;
  __syncthreads();
  float xr[32], yr[32], zr[32];
  int cr[32];
#pragma unroll
  for (int m = 0; m < 32; ++m) {
    int i = m * 256 + t;
    float x = xp[i], y = xp[NPTS + i], z = xp[2 * NPTS + i];
    int xi = max(0, min((int)(x * 8.f), 7));
    int yi = max(0, min((int)(y * 8.f), 7));
    int zi = max(0, min((int)(z * 4.f), 3));
    int c = (zi << 6) | (yi << 3) | xi;
    xr[m] = x; yr[m] = y; zr[m] = z; cr[m] = c;
    atomicAdd(&cnt[c], 1u);
  }
  __syncthreads();
  unsigned v = cnt[t];
  scan[t] = v;
  __syncthreads();
  for (int off = 1; off < 256; off <<= 1) {   // Hillis-Steele inclusive scan
    unsigned u = (t >= off) ? scan[t - off] : 0u;
    __syncthreads();
    scan[t] += u;
    __syncthreads();
  }
  cnt[t] = scan[t] - v;                       // exclusive base -> slot cursor
  __syncthreads();
#pragma unroll
  for (int m = 0; m < 32; ++m) {
    unsigned p = atomicAdd(&cnt[cr[m]], 1u);
    sxy_g[(size_t)b * NPTS + p] = make_float2(xr[m], yr[m]);
    sz_g[(size_t)b * NPTS + p] = zr[m];
    ko_g[(size_t)b * NPTS + p] = (unsigned short)(8191 - (m * 256 + t));
  }
  __syncthreads();                            // drain scatter before re-read
  {
    float mnx = 1e30f, mny = 1e30f, mnz = 1e30f;
    float mxx = -1e30f, mxy = -1e30f, mxz = -1e30f;
    for (int e = 0; e < 32; ++e) {
      float2 xy = sxy_g[(size_t)b * NPTS + t * 32 + e];
      float z = sz_g[(size_t)b * NPTS + t * 32 + e];
      mnx = fminf(mnx, xy.x); mxx = fmaxf(mxx, xy.x);
      mny = fminf(mny, xy.y); mxy = fmaxf(mxy, xy.y);
      mnz = fminf(mnz, z);    mxz = fmaxf(mxz, z);
    }
    float cax = 0.5f * (mnx + mxx), cay = 0.5f * (mny + mxy), caz = 0.5f * (mnz + mxz);
    float* agp = anch_g + ((size_t)b * 256 + t) * 6;
    agp[0] = cax; agp[1] = cay; agp[2] = caz;
    agp[3] = fmaxf(mxx - cax, cax - mnx) * 1.000002f;
    agp[4] = fmaxf(mxy - cay, cay - mny) * 1.000002f;
    agp[5] = fmaxf(mxz - caz, caz - mnz) * 1.000002f;
  }
  if (b != 0) return;
  for (int i = t; i < 8192; i += 256) {
    int o = i >> 6, c = i & 63;
    w3t[c * 128 + o] = w3[i];
  }
  if (t < 64) {
    float s = g1[t] / sqrtf(v1[t] + 1e-5f);
    scsh[t] = s;
    scsh[64 + t] = (b1[t] - m1[t]) * s + t1[t];
    float s2 = g2[t] / sqrtf(v2[t] + 1e-5f);
    scsh[128 + t] = s2;
    scsh[192 + t] = (b2[t] - m2[t]) * s2 + t2[t];
  }
  if (t < 128) {
    float s3 = g3[t] / sqrtf(v3[t] + 1e-5f);
    scsh[256 + t] = s3;
    scsh[384 + t] = (b3[t] - m3[t]) * s3 + t3[t];
  }
}

// ---------------------------------------------------------------------------
// Fused ball-query + gather + MLP(6->64->64->128, BN+ReLU) + max over 32.
// (unchanged: own-wave bq slots, 64KB swizzled act, L3 holds two output-
// channel groups in registers => 1024 ds_read_b128/wave)
// ---------------------------------------------------------------------------
__global__ __launch_bounds__(256, 2) void mlp_kernel(
    const float* __restrict__ xyz, const float* __restrict__ points,
    const float* __restrict__ new_xyz,
    const float* __restrict__ w1, const float* __restrict__ w2,
    const float* __restrict__ w3t, const float* __restrict__ scsh,
    float* __restrict__ out) {
  __shared__ float act[256 * 64];       // exactly 64 KB -> 2 blocks/CU
  float4* act4 = (float4*)act;
  const int tid = threadIdx.x;
  const int wv = tid >> 6, lane = tid & 63;
  const int s0 = blockIdx.x * 8;
  const int b = s0 >> 10;               // 8 | 1024 -> uniform per block
  const int g = tid >> 5;               // center within block
  const int k = tid & 31;               // sample (phase A) / channel lane (L3)
  const int gc = s0 + g;
  const float* xp = xyz + (size_t)b * 3 * NPTS;
  const float* pp = points + (size_t)b * 3 * NPTS;

  // ---- Phase 0: ball query; slots in wave's own 16KB act region ----
  int* slots = (int*)(act + wv * 4096); // 64 ints, overwritten later by act
  {
#pragma clang fp contract(off)
    for (int h = 0; h < 2; ++h) {
      const int hc = s0 + 2 * wv + h;
      const float* cp0 = new_xyz + (size_t)hc * 3;
      const float cx = cp0[0], cy = cp0[1], cz = cp0[2];
      const float asq = (cx * cx + cy * cy) + cz * cz;
      int cnt = 0;
      for (int base = 0; base < NPTS; base += 64) {
        int n = base + lane;
        float x = xp[n], y = xp[NPTS + n], z = xp[2 * NPTS + n];
        float bsq = (x * x + y * y) + z * z;
        float ab = (x * cx + y * cy) + z * cz;
        float sq = (asq + bsq) - 2.0f * ab;
        bool inc = !(sq > 0.01f);       // same f32 threshold as reference
        unsigned long long mk = __ballot(inc);
        int pos = cnt + (int)__popcll(mk & ((1ull << lane) - 1ull));
        if (inc && pos < NSAMPLE) slots[h * 32 + pos] = n;
        cnt += (int)__popcll(mk);
        if (cnt >= NSAMPLE) break;      // wave-uniform
      }
      if (lane < NSAMPLE) {
        int first = slots[h * 32];      // lockstep: all reads before writes
        int v = (lane < cnt) ? slots[h * 32 + lane] : first;
        slots[h * 32 + lane] = v;
      }
    }
  }
  const int n = slots[(g & 1) * 32 + k];  // own-wave slots: no barrier needed

  const float* cp = new_xyz + (size_t)gc * 3;
  float f0 = xp[n] - cp[0];
  float f1 = xp[NPTS + n] - cp[1];
  float f2 = xp[2 * NPTS + n] - cp[2];
  float f3 = pp[n];
  float f4 = pp[NPTS + n];
  float f5 = pp[2 * NPTS + n];
  const float* sc1 = scsh;        const float* sh1 = scsh + 64;
  const float* sc2 = scsh + 128;  const float* sh2 = scsh + 192;
  const float* sc3 = scsh + 256;  const float* sh3 = scsh + 384;
  const int row = tid;

  // ---- L1 ----
#pragma unroll
  for (int oc = 0; oc < 16; ++oc) {
    float va[4];
#pragma unroll
    for (int jj = 0; jj < 4; ++jj) {
      int o = oc * 4 + jj;
      const float* wr = w1 + o * 6;
      float a = f0 * wr[0] + f1 * wr[1] + f2 * wr[2] +
                f3 * wr[3] + f4 * wr[4] + f5 * wr[5];
      va[jj] = fmaxf(a * sc1[o] + sh1[o], 0.f);
    }
    act4[row * 16 + (oc ^ (row & 15))] = make_float4(va[0], va[1], va[2], va[3]);
  }

  // ---- L2 ----
  float acc[64];
#pragma unroll
  for (int o = 0; o < 64; ++o) acc[o] = 0.f;
  for (int cc = 0; cc < 16; ++cc) {
    float4 av = act4[row * 16 + (cc ^ (row & 15))];
#pragma unroll
    for (int o = 0; o < 64; ++o) {
      const float* wr = w2 + o * 64 + cc * 4;
      acc[o] += av.x * wr[0] + av.y * wr[1] + av.z * wr[2] + av.w * wr[3];
    }
  }
#pragma unroll
  for (int oc = 0; oc < 16; ++oc) {
    float va[4];
#pragma unroll
    for (int jj = 0; jj < 4; ++jj) {
      int o = oc * 4 + jj;
      va[jj] = fmaxf(acc[o] * sc2[o] + sh2[o], 0.f);
    }
    act4[row * 16 + (oc ^ (row & 15))] = make_float4(va[0], va[1], va[2], va[3]);
  }
  __syncthreads();

  // ---- L3 + max over k: lane j owns channels {ph*64+j, ph*64+32+j} ----
  const int j = k;
  const int sb = gc & 1023;
  for (int ph = 0; ph < 2; ++ph) {
    int o3a = ph * 64 + j;
    int o3b = o3a + 32;
    float wa[64], wb[64];
#pragma unroll
    for (int c = 0; c < 64; ++c) {
      wa[c] = w3t[c * 128 + o3a];
      wb[c] = w3t[c * 128 + o3b];
    }
    float sca = sc3[o3a], sha = sh3[o3a];
    float scb = sc3[o3b], shb = sh3[o3b];
    float vma = 0.f, vmb = 0.f;
    for (int kk = 0; kk < 32; ++kk) {
      int r2 = g * 32 + kk;
      float a0 = 0.f, a1 = 0.f, a2 = 0.f, a3 = 0.f;
      float b0 = 0.f, b1 = 0.f, b2 = 0.f, b3 = 0.f;
#pragma unroll
      for (int cc = 0; cc < 16; cc += 4) {
        float4 u0 = act4[r2 * 16 + ((cc + 0) ^ (r2 & 15))];
        float4 u1 = act4[r2 * 16 + ((cc + 1) ^ (r2 & 15))];
        float4 u2 = act4[r2 * 16 + ((cc + 2) ^ (r2 & 15))];
        float4 u3 = act4[r2 * 16 + ((cc + 3) ^ (r2 & 15))];
        a0 += u0.x * wa[4*cc+0]  + u0.y * wa[4*cc+1]  + u0.z * wa[4*cc+2]  + u0.w * wa[4*cc+3];
        a1 += u1.x * wa[4*cc+4]  + u1.y * wa[4*cc+5]  + u1.z * wa[4*cc+6]  + u1.w * wa[4*cc+7];
        a2 += u2.x * wa[4*cc+8]  + u2.y * wa[4*cc+9]  + u2.z * wa[4*cc+10] + u2.w * wa[4*cc+11];
        a3 += u3.x * wa[4*cc+12] + u3.y * wa[4*cc+13] + u3.z * wa[4*cc+14] + u3.w * wa[4*cc+15];
        b0 += u0.x * wb[4*cc+0]  + u0.y * wb[4*cc+1]  + u0.z * wb[4*cc+2]  + u0.w * wb[4*cc+3];
        b1 += u1.x * wb[4*cc+4]  + u1.y * wb[4*cc+5]  + u1.z * wb[4*cc+6]  + u1.w * wb[4*cc+7];
        b2 += u2.x * wb[4*cc+8]  + u2.y * wb[4*cc+9]  + u2.z * wb[4*cc+10] + u2.w * wb[4*cc+11];
        b3 += u3.x * wb[4*cc+12] + u3.y * wb[4*cc+13] + u3.z * wb[4*cc+14] + u3.w * wb[4*cc+15];
      }
      float xa = (a0 + a1) + (a2 + a3);
      float xb = (b0 + b1) + (b2 + b3);
      vma = fmaxf(vma, fmaxf(xa * sca + sha, 0.f));
      vmb = fmaxf(vmb, fmaxf(xb * scb + shb, 0.f));
    }
    out[((size_t)b * 128 + o3a) * 1024 + sb] = vma;   // (B,128,1024)
    out[((size_t)b * 128 + o3b) * 1024 + sb] = vmb;
  }
}

// ---------------------------------------------------------------------------
extern "C" void kernel_launch(void* const* d_in, const int* in_sizes, int n_in,
                              void* d_out, int out_size, void* d_ws, size_t ws_size,
                              hipStream_t stream) {
  (void)in_sizes; (void)n_in; (void)out_size; (void)ws_size;
  const float* xyz    = (const float*)d_in[0];
  const float* points = (const float*)d_in[1];
  const float* w1 = (const float*)d_in[2];
  const float* b1 = (const float*)d_in[3];
  const float* g1 = (const float*)d_in[4];
  const float* t1 = (const float*)d_in[5];
  const float* m1 = (const float*)d_in[6];
  const float* v1 = (const float*)d_in[7];
  const float* w2 = (const float*)d_in[8];
  const float* b2 = (const float*)d_in[9];
  const float* g2 = (const float*)d_in[10];
  const float* t2 = (const float*)d_in[11];
  const float* m2 = (const float*)d_in[12];
  const float* v2 = (const float*)d_in[13];
  const float* w3 = (const float*)d_in[14];
  const float* b3 = (const float*)d_in[15];
  const float* g3 = (const float*)d_in[16];
  const float* t3 = (const float*)d_in[17];
  const float* m3 = (const float*)d_in[18];
  const float* v3 = (const float*)d_in[19];

  float* wsf = (float*)d_ws;
  float* new_xyz = wsf;                             // 12288 f
  float* w3t     = wsf + 12288;                     // 8192 f
  float* scsh    = wsf + 20480;                     // 512 f
  float2* sxy_g  = (float2*)(wsf + 20992);          // 4*8192 float2 = 65536 f
  float* sz_g    = wsf + 86528;                     // 32768 f
  unsigned short* ko_g = (unsigned short*)(wsf + 119296);  // 32768 u16
  float* anch_g  = wsf + 135680;                    // 6144 f
  float* out     = (float*)d_out;                   // (4,128,1024) f32

  hipFuncSetAttribute(reinterpret_cast<const void*>(fps_kernel),
                      hipFuncAttributeMaxDynamicSharedMemorySize, 154688);

  hipLaunchKernelGGL(setup_kernel, dim3(4), dim3(256), 0, stream,
                     xyz, w3, b1, g1, t1, m1, v1, b2, g2, t2, m2, v2,
                     b3, g3, t3, m3, v3, sxy_g, sz_g, ko_g, anch_g, w3t, scsh);
  hipLaunchKernelGGL(fps_kernel, dim3(4), dim3(256), 154688, stream,
                     xyz, sxy_g, sz_g, (const unsigned*)ko_g, anch_g, new_xyz);
  hipLaunchKernelGGL(mlp_kernel, dim3(512), dim3(256), 0, stream,
                     xyz, points, new_xyz, w1, w2, w3t, scsh, out);
}